// Round 15
// baseline (1818.481 us; speedup 1.0000x reference)
//
#include <hip/hip_runtime.h>
#include <math.h>

// PrattRNNLayer: ns_t = sqrt(cos^2(x_t@K) + sin^2(s_{t-1}@R)), out = ns*(1-ns^2).
// B=128, T=2048, D=128, fp32.
//
// Round-14 "config S" (evidence: R13 step = 926 cyc; per-step LDS traffic was
// 64KB (512thr x 128B) to broadcast a 512B state -> ~400-770 cyc on the LDS
// pipe, plus 2 dependent shuffles + 8-wave barrier):
//  K2 serial: 128 threads (2 waves), thread d owns column R[:,d] in 128 VGPRs
//   and computes the FULL 128-dot -> no shuffles; state reads are wave-UNIFORM
//   addresses (LDS broadcast, 64 lanes/fetch) -> LDS traffic 64KB -> 1KB/step;
//   barrier syncs 2 waves not 8. GROUP=16 km-prefetch/out-batching kept.
//  K1 prepass: unchanged from R13 (proven).

constexpr int Bb = 128;
constexpr int Tt = 2048;
constexpr int Dd = 128;
constexpr int PP_ROWS = 128;   // prepass rows per block
constexpr int GROUP = 16;      // serial steps per km-prefetch group

// ---------- K1: kmT[b][d][t] = sum_k x[b,t,k] K[k,d] ----------
__global__ __launch_bounds__(256, 2)
void pratt_prepass(const float* __restrict__ x,
                   const float* __restrict__ Kmat,
                   float* __restrict__ kmT)
{
    __shared__ float Ks[Dd][Dd];   // 64 KiB: K staged ONCE per block
    {
        const float4* Kg  = reinterpret_cast<const float4*>(Kmat);
        float4*       KsV = reinterpret_cast<float4*>(&Ks[0][0]);
#pragma unroll
        for (int j = 0; j < 16; ++j)
            KsV[threadIdx.x + j * 256] = Kg[threadIdx.x + j * 256];
    }
    __syncthreads();

    const int  rgrp = threadIdx.x >> 4;                    // 0..15 -> 8 rows
    const int  cgrp = threadIdx.x & 15;                    // 0..15 -> 8 cols
    const int  c0   = cgrp << 3;
    const long row0 = (long)blockIdx.x * PP_ROWS + (long)rgrp * 8;

    const float4* xr[8];
#pragma unroll
    for (int r = 0; r < 8; ++r)
        xr[r] = reinterpret_cast<const float4*>(x + (size_t)(row0 + r) * Dd);

    float acc[8][8];
#pragma unroll
    for (int r = 0; r < 8; ++r)
#pragma unroll
        for (int c = 0; c < 8; ++c) acc[r][c] = 0.f;

    for (int k4 = 0; k4 < Dd / 4; ++k4) {
        float4 xq[8];
#pragma unroll
        for (int r = 0; r < 8; ++r) xq[r] = xr[r][k4];
        float4 kf[4][2];
#pragma unroll
        for (int kk = 0; kk < 4; ++kk) {
            const float* krow = &Ks[k4 * 4 + kk][c0];
            kf[kk][0] = *reinterpret_cast<const float4*>(krow);
            kf[kk][1] = *reinterpret_cast<const float4*>(krow + 4);
        }
#pragma unroll
        for (int kk = 0; kk < 4; ++kk) {
#pragma unroll
            for (int r = 0; r < 8; ++r) {
                const float xv = (kk == 0) ? xq[r].x : (kk == 1) ? xq[r].y
                               : (kk == 2) ? xq[r].z : xq[r].w;
                acc[r][0] = fmaf(xv, kf[kk][0].x, acc[r][0]);
                acc[r][1] = fmaf(xv, kf[kk][0].y, acc[r][1]);
                acc[r][2] = fmaf(xv, kf[kk][0].z, acc[r][2]);
                acc[r][3] = fmaf(xv, kf[kk][0].w, acc[r][3]);
                acc[r][4] = fmaf(xv, kf[kk][1].x, acc[r][4]);
                acc[r][5] = fmaf(xv, kf[kk][1].y, acc[r][5]);
                acc[r][6] = fmaf(xv, kf[kk][1].z, acc[r][6]);
                acc[r][7] = fmaf(xv, kf[kk][1].w, acc[r][7]);
            }
        }
    }

    // transposed store: 16 blocks per batch (2048/128), block fully in one b
    const int b   = blockIdx.x >> 4;
    const int t00 = (blockIdx.x & 15) * PP_ROWS + rgrp * 8;   // t of r=0
#pragma unroll
    for (int c = 0; c < 8; ++c) {
        float* p = kmT + ((size_t)b * Dd + (c0 + c)) * Tt + t00;
        *reinterpret_cast<float4*>(p)     = make_float4(acc[0][c], acc[1][c], acc[2][c], acc[3][c]);
        *reinterpret_cast<float4*>(p + 4) = make_float4(acc[4][c], acc[5][c], acc[6][c], acc[7][c]);
    }
}

// ---------- K2: serial recurrence, one block (2 waves) per batch row ----------
__global__ __launch_bounds__(128)
void pratt_rnn(const float* __restrict__ kmT,
               const float* __restrict__ Rmat,
               float* __restrict__ out)
{
    const int d = threadIdx.x;    // 0..127: this thread owns feature d

    // Column d of R in registers (coalesced across lanes per k; one-time).
    float Rr[Dd];
#pragma unroll
    for (int k = 0; k < Dd; ++k) Rr[k] = Rmat[k * Dd + d];

    __shared__ __align__(16) float sbuf[2][Dd];
    sbuf[0][d] = 0.0f;            // s0 = zeros
    __syncthreads();

    const float* kmd = kmT + ((size_t)blockIdx.x * Dd + d) * Tt;
    float*       ob  = out + (size_t)blockIdx.x * Tt * Dd;

    // preload group 0 (16 km values, 64B contiguous per thread)
    float4 cur0 = *reinterpret_cast<const float4*>(kmd + 0);
    float4 cur1 = *reinterpret_cast<const float4*>(kmd + 4);
    float4 cur2 = *reinterpret_cast<const float4*>(kmd + 8);
    float4 cur3 = *reinterpret_cast<const float4*>(kmd + 12);

    for (int g = 0; g < Tt / GROUP; ++g) {
        // issue next group's km loads; drained once at this group's first barrier
        const int gn = (g + 1 < Tt / GROUP) ? g + 1 : g;
        const float* pn = kmd + (size_t)gn * GROUP;
        const float4 nx0 = *reinterpret_cast<const float4*>(pn + 0);
        const float4 nx1 = *reinterpret_cast<const float4*>(pn + 4);
        const float4 nx2 = *reinterpret_cast<const float4*>(pn + 8);
        const float4 nx3 = *reinterpret_cast<const float4*>(pn + 12);

        float ovals[GROUP];            // static-indexed under full unroll
        const int tbase = g * GROUP;

#pragma unroll
        for (int j = 0; j < GROUP; ++j) {
            const float4 qs  = (j < 4) ? cur0 : (j < 8) ? cur1 : (j < 12) ? cur2 : cur3;
            const int    jm  = j & 3;
            const float  kmv = (jm == 0) ? qs.x : (jm == 1) ? qs.y : (jm == 2) ? qs.z : qs.w;
            const int    rb  = j & 1;  // double-buffer parity (GROUP even)

            // full 128-dot: state read at WAVE-UNIFORM addresses (broadcast),
            // weights per-lane in VGPRs. 8 independent FMA chains.
            const float4* sv4 = reinterpret_cast<const float4*>(&sbuf[rb][0]);
            float acc[8];
#pragma unroll
            for (int a = 0; a < 8; ++a) acc[a] = 0.f;
#pragma unroll
            for (int k4 = 0; k4 < Dd / 4; ++k4) {
                const float4 sv = sv4[k4];          // same addr for all 64 lanes
                const int a = k4 & 7;               // static under unroll
                acc[a] = fmaf(sv.x, Rr[4*k4+0], acc[a]);
                acc[a] = fmaf(sv.y, Rr[4*k4+1], acc[a]);
                acc[a] = fmaf(sv.z, Rr[4*k4+2], acc[a]);
                acc[a] = fmaf(sv.w, Rr[4*k4+3], acc[a]);
            }
            const float rc = ((acc[0] + acc[1]) + (acc[2] + acc[3]))
                           + ((acc[4] + acc[5]) + (acc[6] + acc[7]));

            const float cc = __cosf(kmv);
            const float ss = __sinf(rc);
            const float ns = __builtin_amdgcn_sqrtf(fmaf(cc, cc, ss * ss));
            ovals[j] = ns * (1.0f - ns * ns);

            sbuf[rb ^ 1][d] = ns;     // publish state (stride-1, conflict-free)
            __syncthreads();          // 2-wave barrier, one per step
        }

        // batched output store (drained at next group's first barrier)
#pragma unroll
        for (int j = 0; j < GROUP; ++j)
            ob[(size_t)(tbase + j) * Dd + d] = ovals[j];

        cur0 = nx0; cur1 = nx1; cur2 = nx2; cur3 = nx3;
    }
}

// ---------- fallback (proven-correct fused kernel) if ws is too small ----------
__global__ __launch_bounds__(512, 2)
void pratt_fused(const float* __restrict__ x,
                 const float* __restrict__ Kmat,
                 const float* __restrict__ Rmat,
                 float* __restrict__ out)
{
    const int b   = blockIdx.x;
    const int tid = threadIdx.x;
    const int d   = tid >> 2;
    const int kq  = tid & 3;
    const int k0  = kq << 5;

    float Kr[32], Rr[32];
#pragma unroll
    for (int i = 0; i < 32; ++i) {
        Kr[i] = Kmat[(k0 + i) * Dd + d];
        Rr[i] = Rmat[(k0 + i) * Dd + d];
    }
    __shared__ float sbuf[2][Dd];
    if (tid < Dd) sbuf[0][tid] = 0.0f;
    __syncthreads();

    const float* xb = x   + (size_t)b * Tt * Dd;
    float*       ob = out + (size_t)b * Tt * Dd;
    int cur = 0;
    for (int t = 0; t < Tt; ++t) {
        const float4* xr = reinterpret_cast<const float4*>(xb + (size_t)t * Dd) + (k0 >> 2);
        const float4* s4 = reinterpret_cast<const float4*>(&sbuf[cur][k0]);
        float ka = 0.f, ra = 0.f;
#pragma unroll
        for (int i = 0; i < 8; ++i) {
            const float4 xv = xr[i];
            const float4 sv = s4[i];
            ka = fmaf(xv.x, Kr[4*i+0], ka); ka = fmaf(xv.y, Kr[4*i+1], ka);
            ka = fmaf(xv.z, Kr[4*i+2], ka); ka = fmaf(xv.w, Kr[4*i+3], ka);
            ra = fmaf(sv.x, Rr[4*i+0], ra); ra = fmaf(sv.y, Rr[4*i+1], ra);
            ra = fmaf(sv.z, Rr[4*i+2], ra); ra = fmaf(sv.w, Rr[4*i+3], ra);
        }
        ka += __shfl_xor(ka, 1); ka += __shfl_xor(ka, 2);
        ra += __shfl_xor(ra, 1); ra += __shfl_xor(ra, 2);
        const float cc = cosf(ka), ss = sinf(ra);
        const float ns = sqrtf(fmaf(cc, cc, ss * ss));
        const float o  = ns * (1.0f - ns * ns);
        const int nxt = cur ^ 1;
        if (kq == 0) sbuf[nxt][d] = ns;
        if (kq == 1) ob[(size_t)t * Dd + d] = o;
        __syncthreads();
        cur = nxt;
    }
}

extern "C" void kernel_launch(void* const* d_in, const int* in_sizes, int n_in,
                              void* d_out, int out_size, void* d_ws, size_t ws_size,
                              hipStream_t stream)
{
    const float* x = (const float*)d_in[0];   // [128, 2048, 128] f32
    const float* K = (const float*)d_in[1];   // [128, 128] f32
    const float* R = (const float*)d_in[2];   // [128, 128] f32
    float* out = (float*)d_out;

    const size_t km_bytes = (size_t)Bb * Tt * Dd * sizeof(float);  // 128 MB
    if (ws_size >= km_bytes) {
        float* kmT = (float*)d_ws;
        pratt_prepass<<<dim3(Bb * Tt / PP_ROWS), dim3(256), 0, stream>>>(x, K, kmT);
        pratt_rnn<<<dim3(Bb), dim3(128), 0, stream>>>(kmT, R, out);
    } else {
        pratt_fused<<<dim3(Bb), dim3(512), 0, stream>>>(x, K, R, out);
    }
}